// Round 10
// baseline (108.754 us; speedup 1.0000x reference)
//
#include <hip/hip_runtime.h>
#include <math.h>

#define W_ 128
#define H_ 96
#define C_ 128
#define HW_ (H_ * W_)          // 12288
#define K_ 81
#define FLOW_ELEMS (2 * 2 * H_ * W_)   // 49152

// Fused kernel: one 576-thread block (9 waves) per (b, y0) row.
// Wave dg (0..8) accumulates ALL 128 channels of halo row r = y0+dg-4 into
// registers (k-slice [dg*9, dg*9+9) for all 128 px) using its private LDS
// staging slice -- byte-identical inner loop to the verified R7 corr kernel.
// Then: block barrier -> corr tile in LDS -> per-px softmax + flow ->
// coalesced match_prob writeout. No scratch, no second kernel.
// Grid = 192 blocks (8 XCD chunks x 24). Lane owns px x = 2*lane, 2*lane+1.
__global__ __launch_bounds__(576, 1) void fused_kernel(const float* __restrict__ f0,
                                                       const float* __restrict__ f1,
                                                       float* __restrict__ out) {
    __shared__ union {
        float stage[9][8][136];                    // 39168 B: per-wave staging
        struct {
            float tile[128][83];                   // 42496 B: corr, odd stride
            float mbuf[128];
            float ibuf[128];
        } sm;
    } u;

    const int t = threadIdx.x;
    const int dg = t >> 6;               // wave id = dy group, 0..8
    const int lane = t & 63;

    // XCD-bijective swizzle: 192 = 8 * 24
    const int L = (blockIdx.x & 7) * 24 + (blockIdx.x >> 3);
    const int y0 = L % H_;
    const int b  = L / H_;
    const int r  = y0 + dg - 4;          // halo row in f1 (may be OOB)
    const bool rok = (r >= 0) && (r < H_);

    // staging: lane q stages quad q covering f1 columns q*4-4 .. q*4-1;
    // LDS word w holds column w-4. Quads 0 and 33 are fully OOB -> zeros.
    const int q = lane;
    const bool qok = rok && (q >= 1) && (q <= 32);
    const float* f0p = f0 + (size_t)b * C_ * HW_ + (size_t)y0 * W_ + 2 * lane;
    const float* f1p = f1 + (size_t)b * C_ * HW_ + (size_t)(rok ? r : 0) * W_ + (q * 4 - 4);

    float acc0[9], acc1[9];
#pragma unroll
    for (int j = 0; j < 9; ++j) { acc0[j] = 0.f; acc1[j] = 0.f; }

    // ---- load chunk ck (8 channels) into named register set ----
    auto LOAD = [&](int ck, float4 (&v)[8], float2 (&g)[8]) {
#pragma unroll
        for (int cc = 0; cc < 8; ++cc) {
            const size_t co = (size_t)(ck * 8 + cc) * HW_;
            g[cc] = *(const float2*)(f0p + co);
            float4 tv = make_float4(0.f, 0.f, 0.f, 0.f);
            if (qok) tv = *(const float4*)(f1p + co);
            v[cc] = tv;
        }
    };

    // ---- stage to private LDS slice (fence-only; 1-wave DS-pipe order) ----
    auto CONSUME = [&](const float4 (&v)[8], const float2 (&g)[8]) {
        __builtin_amdgcn_sched_barrier(0);
        if (q < 34) {
#pragma unroll
            for (int cc = 0; cc < 8; ++cc)
                *(float4*)&u.stage[dg][cc][q * 4] = v[cc];
        }
        __builtin_amdgcn_sched_barrier(0);
#pragma unroll
        for (int cc = 0; cc < 8; ++cc) {
            const float2* row = (const float2*)(&u.stage[dg][cc][0]) + lane;
            const float2 w0 = row[0], w1 = row[1], w2 = row[2],
                         w3 = row[3], w4 = row[4];
            const float vv[10] = {w0.x, w0.y, w1.x, w1.y, w2.x,
                                  w2.y, w3.x, w3.y, w4.x, w4.y};
#pragma unroll
            for (int dx = 0; dx < 9; ++dx) {
                acc0[dx] += g[cc].x * vv[dx];
                acc1[dx] += g[cc].y * vv[dx + 1];
            }
        }
    };

    float4 vA[8], vB[8];
    float2 gA[8], gB[8];

    // 16 chunks: A consumes 0,2,...,14; B consumes 1,3,...,15.
    LOAD(0, vA, gA);
    for (int it = 0; it < 8; ++it) {
        LOAD(2 * it + 1, vB, gB);
        CONSUME(vA, gA);
        if (it < 7) LOAD(2 * it + 2, vA, gA);
        CONSUME(vB, gB);
    }

    // ---- corr done (in regs). Repurpose LDS as the corr tile. ----
    __syncthreads();                     // all staging reads complete
#pragma unroll
    for (int j = 0; j < 9; ++j) {
        u.sm.tile[2 * lane][dg * 9 + j] = acc0[j];
        u.sm.tile[2 * lane + 1][dg * 9 + j] = acc1[j];
    }
    __syncthreads();                     // tile fully written

    const float scale = 0.08838834764831845f;   // 1/sqrt(128)

    // ---- pass 1: thread-per-px (t < 128) max / sum-exp / flow ----
    if (t < 128) {
        const int px = t;
        float m = -1e30f;
#pragma unroll 9
        for (int k = 0; k < K_; ++k) m = fmaxf(m, u.sm.tile[px][k] * scale);
        float s = 0.f, fx = 0.f, fy = 0.f;
#pragma unroll 9
        for (int k = 0; k < K_; ++k) {
            const float e = __expf(u.sm.tile[px][k] * scale - m);
            s += e;
            fx += e * (float)(k % 9 - 4);
            fy += e * (float)(k / 9 - 4);
        }
        const float inv = 1.f / s;
        u.sm.mbuf[px] = m;
        u.sm.ibuf[px] = inv;
        const size_t fbase = (size_t)b * 2 * HW_ + (size_t)y0 * W_ + px;
        out[fbase] = fx * inv;
        out[fbase + HW_] = fy * inv;
    }
    __syncthreads();

    // ---- pass 2: all 576 threads write match_prob coalesced ----
    float* mp = out + FLOW_ELEMS + ((size_t)b * HW_ + (size_t)y0 * W_) * K_;
    for (int i = t; i < 128 * K_; i += 576) {
        const int px = i / K_;
        const int k = i - px * K_;
        mp[i] = __expf(u.sm.tile[px][k] * scale - u.sm.mbuf[px]) * u.sm.ibuf[px];
    }
}

extern "C" void kernel_launch(void* const* d_in, const int* in_sizes, int n_in,
                              void* d_out, int out_size, void* d_ws, size_t ws_size,
                              hipStream_t stream) {
    (void)in_sizes; (void)n_in; (void)d_ws; (void)ws_size; (void)out_size;
    const float* f0 = (const float*)d_in[0];
    const float* f1 = (const float*)d_in[1];
    float* out = (float*)d_out;

    fused_kernel<<<192, 576, 0, stream>>>(f0, f1, out);
}

// Round 12
// 36.602 us; speedup vs baseline: 2.9713x; 2.9713x over previous
//
#include <hip/hip_runtime.h>
#include <math.h>

#define W_ 128
#define H_ 96
#define C_ 128
#define HW_ (H_ * W_)          // 12288
#define K_ 81
#define FLOW_ELEMS (2 * 2 * H_ * W_)   // 49152

typedef __fp16 half2_t __attribute__((ext_vector_type(2)));

__device__ __forceinline__ half2_t pkrtz(float a, float b) {
    return __builtin_amdgcn_cvt_pkrtz(a, b);   // v_cvt_pkrtz_f16_f32
}

__device__ __forceinline__ float dot2(half2_t a, unsigned bw, float c) {
    const half2_t b = __builtin_bit_cast(half2_t, bw);
#if __has_builtin(__builtin_amdgcn_fdot2)
    return __builtin_amdgcn_fdot2(a, b, c, false);   // v_dot2_f32_f16
#else
    return fmaf((float)a.x, (float)b.x, fmaf((float)a.y, (float)b.y, c));
#endif
}

// Corr kernel, dy-sliced (R7-verified decomposition): one 64-thread block
// (= one wave) per (b, y0, dg), dg in 0..8 -> dy = dg-4. The wave accumulates
// ALL 128 channels for halo row r = y0+dg-4 and writes the disjoint k-slice
// [dg*9, dg*9+9) of corr for all 128 pixels of row y0.
// Round 12: f16 packed dot2 -- channels processed in PAIRS (v_dot2_f32_f16),
// halving VALU ops, LDS words, and the serial chunk chain (8 chunks of 16 ch).
// LDS u32 word (j, w) = f16 pair {f1[c0+2j][w-4], f1[c0+2j+1][w-4]}.
// Lane owns pixels x = 2*lane, 2*lane+1. Grid = 1728 blocks (8 XCD chunks x 216).
__global__ __launch_bounds__(64) void corr_kernel(const float* __restrict__ f0,
                                                  const float* __restrict__ f1,
                                                  float* __restrict__ corr) {
    __shared__ unsigned lds[8][136];   // 8 c-pairs x 136 halo cols (4352 B)

    const int lane = threadIdx.x;

    // XCD-bijective swizzle: 1728 = 8 * 216
    const int L = (blockIdx.x & 7) * 216 + (blockIdx.x >> 3);
    const int dg = L % 9;
    const int rid = L / 9;               // 0..191
    const int y0 = rid % H_;
    const int b  = rid / H_;
    const int r  = y0 + dg - 4;          // halo row in f1 (may be OOB)
    const bool rok = (r >= 0) && (r < H_);

    // staging: lane q stages quad q covering f1 columns q*4-4 .. q*4-1;
    // word w holds column w-4. Quads 0 and 33 are fully OOB -> zeros.
    const int q = lane;
    const bool qok = rok && (q >= 1) && (q <= 32);
    const float* f0p = f0 + (size_t)b * C_ * HW_ + (size_t)y0 * W_ + 2 * lane;
    const float* f1p = f1 + (size_t)b * C_ * HW_ + (size_t)(rok ? r : 0) * W_ + (q * 4 - 4);

    float acc0[9], acc1[9];
#pragma unroll
    for (int j = 0; j < 9; ++j) { acc0[j] = 0.f; acc1[j] = 0.f; }

    for (int ck = 0; ck < 8; ++ck) {
        // ---- load 16 channels (f0 px-pair + f1 col-quad) ----
        float4 v[16];
        float2 g[16];
#pragma unroll
        for (int cc = 0; cc < 16; ++cc) {
            const size_t co = (size_t)(ck * 16 + cc) * HW_;
            g[cc] = *(const float2*)(f0p + co);
            float4 t = make_float4(0.f, 0.f, 0.f, 0.f);
            if (qok) t = *(const float4*)(f1p + co);
            v[cc] = t;
        }

        // ---- pack channel pairs to f16x2 ----
        half2_t a0[8], a1[8];      // f0 for px 2*lane, 2*lane+1
        uint4 pw[8];               // f1: 4 packed cols per c-pair
#pragma unroll
        for (int j = 0; j < 8; ++j) {
            a0[j] = pkrtz(g[2 * j].x, g[2 * j + 1].x);
            a1[j] = pkrtz(g[2 * j].y, g[2 * j + 1].y);
            pw[j].x = __builtin_bit_cast(unsigned, pkrtz(v[2 * j].x, v[2 * j + 1].x));
            pw[j].y = __builtin_bit_cast(unsigned, pkrtz(v[2 * j].y, v[2 * j + 1].y));
            pw[j].z = __builtin_bit_cast(unsigned, pkrtz(v[2 * j].z, v[2 * j + 1].z));
            pw[j].w = __builtin_bit_cast(unsigned, pkrtz(v[2 * j].w, v[2 * j + 1].w));
        }

        // ---- stage to LDS (fence-only; 1-wave block, DS-pipe order) ----
        __builtin_amdgcn_sched_barrier(0);
        if (q < 34) {
#pragma unroll
            for (int j = 0; j < 8; ++j)
                *(uint4*)&lds[j][q * 4] = pw[j];
        }
        __builtin_amdgcn_sched_barrier(0);

        // ---- consume: per c-pair, 10 packed cols feed 18 dot2 ----
#pragma unroll
        for (int j = 0; j < 8; ++j) {
            const uint2* row = (const uint2*)(&lds[j][0]) + lane;
            const uint2 w0 = row[0], w1 = row[1], w2 = row[2],
                        w3 = row[3], w4 = row[4];
            const unsigned vv[10] = {w0.x, w0.y, w1.x, w1.y, w2.x,
                                     w2.y, w3.x, w3.y, w4.x, w4.y};
#pragma unroll
            for (int dx = 0; dx < 9; ++dx) {
                acc0[dx] = dot2(a0[j], vv[dx], acc0[dx]);
                acc1[dx] = dot2(a1[j], vv[dx + 1], acc1[dx]);
            }
        }
    }

    // disjoint k-slice writeout; OOB-row waves naturally wrote acc==0
    float* cb = corr + ((size_t)b * HW_ + (size_t)y0 * W_ + 2 * lane) * K_ + dg * 9;
#pragma unroll
    for (int j = 0; j < 9; ++j) cb[j] = acc0[j];
#pragma unroll
    for (int j = 0; j < 9; ++j) cb[K_ + j] = acc1[j];
}

// Kernel 2: scale by 1/sqrt(128), softmax over K in-place, prob + flow.
// (verified in R5; unchanged)
__global__ __launch_bounds__(256) void softmax_kernel(float* __restrict__ out) {
    const int t = threadIdx.x;
    const int wave = t >> 6, lane = t & 63;
    const int px = (blockIdx.x << 2) + wave;      // 0 .. 24575
    const int b = px / HW_;
    const int pl = px - b * HW_;
    const int y = pl >> 7, x = pl & 127;

    float* corr = out + FLOW_ELEMS + (size_t)px * K_;
    const float scale = 0.08838834764831845f;     // 1/sqrt(128)

    const bool has1 = lane < (K_ - 64);           // lane < 17
    float v0 = corr[lane] * scale;
    float v1 = has1 ? corr[lane + 64] * scale : -1e30f;

    float m = fmaxf(v0, v1);
#pragma unroll
    for (int off = 32; off; off >>= 1) m = fmaxf(m, __shfl_xor(m, off));

    float e0 = __expf(v0 - m);
    float e1 = has1 ? __expf(v1 - m) : 0.f;
    float s = e0 + e1;
#pragma unroll
    for (int off = 32; off; off >>= 1) s += __shfl_xor(s, off);

    const float inv = 1.f / s;
    const float p0 = e0 * inv;
    const float p1 = e1 * inv;

    corr[lane] = p0;
    if (has1) corr[lane + 64] = p1;

    float fx = p0 * (float)(lane % 9 - 4) + p1 * (float)((lane + 64) % 9 - 4);
    float fy = p0 * (float)(lane / 9 - 4) + p1 * (float)((lane + 64) / 9 - 4);
#pragma unroll
    for (int off = 32; off; off >>= 1) {
        fx += __shfl_xor(fx, off);
        fy += __shfl_xor(fy, off);
    }

    if (lane == 0) {
        out[((size_t)(b * 2 + 0) * H_ + y) * W_ + x] = fx;
        out[((size_t)(b * 2 + 1) * H_ + y) * W_ + x] = fy;
    }
}

extern "C" void kernel_launch(void* const* d_in, const int* in_sizes, int n_in,
                              void* d_out, int out_size, void* d_ws, size_t ws_size,
                              hipStream_t stream) {
    (void)in_sizes; (void)n_in; (void)d_ws; (void)ws_size; (void)out_size;
    const float* f0 = (const float*)d_in[0];
    const float* f1 = (const float*)d_in[1];
    float* out = (float*)d_out;

    corr_kernel<<<1728, 64, 0, stream>>>(f0, f1, out + FLOW_ELEMS);
    softmax_kernel<<<6144, 256, 0, stream>>>(out);
}